// Round 8
// baseline (122.362 us; speedup 1.0000x reference)
//
#include <hip/hip_runtime.h>
#include <hip/hip_bf16.h>

#define D 128
#define REP 8   // sub-bins per dst: kills same-address atomic serialization

using bf16x8 = __attribute__((ext_vector_type(8))) short;
using f32x4  = __attribute__((ext_vector_type(4))) float;

__device__ __forceinline__ ushort bf16bits(float f) {
    return __hip_bfloat16_raw(__float2bfloat16(f)).x;
}
__device__ __forceinline__ uint pack2(float lo, float hi) {
    return ((uint)bf16bits(hi) << 16) | (uint)bf16bits(lo);
}

// ---- prep: block0 = fold (v = W_taste@a_dst, consts); blocks1-2 = Wt = bf16(W_ing^T);
//      blocks3+ = zero count8/total
__global__ __launch_bounds__(256)
void prep_kernel(const float* __restrict__ W_ing, const float* __restrict__ b_ing,
                 const float* __restrict__ W_taste, const float* __restrict__ b_taste,
                 const float* __restrict__ a_src, const float* __restrict__ a_dst,
                 ushort* __restrict__ Wt, float* __restrict__ v, float* __restrict__ consts,
                 int* __restrict__ count8, int* __restrict__ total, int nt) {
    int t = threadIdx.x, b = blockIdx.x;
    if (b == 0) {
        __shared__ float red[D];
        int k = t;
        if (k < D) {
            float sv = 0.f;
            for (int d2 = 0; d2 < D; ++d2) sv += W_taste[k * D + d2] * a_dst[d2];
            v[k] = sv;
            red[k] = b_ing[k] * a_src[k];
        }
        __syncthreads();
        for (int s = 64; s > 0; s >>= 1) { if (k < s) red[k] += red[k + s]; __syncthreads(); }
        if (k == 0) consts[0] = red[0];
        __syncthreads();
        if (k < D) red[k] = b_taste[k] * a_dst[k];
        __syncthreads();
        for (int s = 64; s > 0; s >>= 1) { if (k < s) red[k] += red[k + s]; __syncthreads(); }
        if (k == 0) consts[1] = red[0];
    } else if (b <= 2) {
        int base = (b - 1) * 8192 + t * 32;
        #pragma unroll 8
        for (int i = 0; i < 32; ++i) {
            int idx = base + i;
            int n = idx >> 7, k = idx & 127;
            Wt[n * D + k] = bf16bits(W_ing[k * D + n]);
        }
    } else {
        int gid = (b - 3) * 256 + t;
        int nbins = nt * REP;
        if (gid < nbins) count8[gid] = 0;
        if (gid == nbins) *total = 0;
    }
}

// ---- MFMA GEMM: h16 = bf16(x @ W_ing + b), fused al = h·a_src + consts[0]
__global__ __launch_bounds__(256)
void gemm_mfma(const float* __restrict__ x, const ushort* __restrict__ Wt,
               const float* __restrict__ b, const float* __restrict__ avec,
               const float* __restrict__ consts,
               ushort* __restrict__ h16, float* __restrict__ al, int nrows) {
    __shared__ __align__(16) ushort Xs[128 * 128];
    __shared__ __align__(16) ushort Ws[128 * 128];
    int t = threadIdx.x;
    int row0 = blockIdx.x * 128;

    {   // stage X (fp32 -> bf16) and Wt (bf16), 16B-chunk XOR-swizzled by (row&7)
        int r = t >> 1;
        int kh = (t & 1) * 64;
        const float* xp = x + (size_t)(row0 + r) * D + kh;
        bool valid = (row0 + r) < nrows;
        const ushort* wp = Wt + (size_t)r * D + kh;
        int base_us = r * 128;
        #pragma unroll
        for (int j = 0; j < 8; ++j) {
            int c16 = (kh >> 3) + j;
            int off = base_us + ((c16 ^ (r & 7)) << 3);
            float4 a = valid ? *(const float4*)(xp + j * 8)     : make_float4(0.f, 0.f, 0.f, 0.f);
            float4 c = valid ? *(const float4*)(xp + j * 8 + 4) : make_float4(0.f, 0.f, 0.f, 0.f);
            uint4 pk;
            pk.x = pack2(a.x, a.y); pk.y = pack2(a.z, a.w);
            pk.z = pack2(c.x, c.y); pk.w = pack2(c.z, c.w);
            *(uint4*)&Xs[off] = pk;
            *(uint4*)&Ws[off] = *(const uint4*)(wp + j * 8);
        }
    }
    __syncthreads();

    int l = t & 63, w = t >> 6;
    int lr = l & 15, lq = l >> 4;
    f32x4 acc[2][8];
    #pragma unroll
    for (int i = 0; i < 2; ++i)
        #pragma unroll
        for (int j = 0; j < 8; ++j) acc[i][j] = f32x4{0.f, 0.f, 0.f, 0.f};

    int rowA0 = w * 32 + lr;
    int rowA1 = rowA0 + 16;
    int sw = lr & 7;
    #pragma unroll
    for (int s = 0; s < 4; ++s) {
        int c16 = s * 4 + lq;
        bf16x8 A0 = *(const bf16x8*)&Xs[rowA0 * 128 + ((c16 ^ sw) << 3)];
        bf16x8 A1 = *(const bf16x8*)&Xs[rowA1 * 128 + ((c16 ^ sw) << 3)];
        #pragma unroll
        for (int ct = 0; ct < 8; ++ct) {
            int rn = ct * 16 + lr;
            bf16x8 B = *(const bf16x8*)&Ws[rn * 128 + ((c16 ^ sw) << 3)];
            acc[0][ct] = __builtin_amdgcn_mfma_f32_16x16x32_bf16(A0, B, acc[0][ct], 0, 0, 0);
            acc[1][ct] = __builtin_amdgcn_mfma_f32_16x16x32_bf16(A1, B, acc[1][ct], 0, 0, 0);
        }
    }

    float bv[8], av[8];
    #pragma unroll
    for (int ct = 0; ct < 8; ++ct) { bv[ct] = b[ct * 16 + lr]; av[ct] = avec[ct * 16 + lr]; }
    float c0 = consts[0];
    #pragma unroll
    for (int rt = 0; rt < 2; ++rt) {
        #pragma unroll
        for (int r = 0; r < 4; ++r) {
            int gr = row0 + w * 32 + rt * 16 + lq * 4 + r;
            float p = 0.f;
            ushort hrow[8];
            #pragma unroll
            for (int ct = 0; ct < 8; ++ct) {
                float hv = acc[rt][ct][r] + bv[ct];
                p = fmaf(hv, av[ct], p);
                hrow[ct] = bf16bits(hv);
            }
            p += __shfl_xor(p, 1, 64); p += __shfl_xor(p, 2, 64);
            p += __shfl_xor(p, 4, 64); p += __shfl_xor(p, 8, 64);
            if (gr < nrows) {
                #pragma unroll
                for (int ct = 0; ct < 8; ++ct)
                    h16[(size_t)gr * D + ct * 16 + lr] = hrow[ct];
                if (lr == 0) al[gr] = p + c0;
            }
        }
    }
}

// ---- fused: blocks [0,512) = al_dst matvec; blocks [512,2048) = dst histogram
// hist uses REP sub-bins per dst (by edge index) and persists the rank.
__global__ __launch_bounds__(256)
void mh_kernel(const float* __restrict__ x_taste, const float* __restrict__ v,
               const float* __restrict__ consts, int nt, float* __restrict__ al_dst,
               const int* __restrict__ dstv, int E, int* __restrict__ count8,
               int* __restrict__ rank) {
    if (blockIdx.x < 512) {
        int lane = threadIdx.x & 63;
        int wave = blockIdx.x * 4 + (threadIdx.x >> 6);
        float2 uv = ((const float2*)v)[lane];
        float c = consts[1];
        for (int r = wave; r < nt; r += 2048) {
            float2 xv = ((const float2*)(x_taste + (size_t)r * D))[lane];
            float p = xv.x * uv.x + xv.y * uv.y;
            #pragma unroll
            for (int off = 32; off; off >>= 1) p += __shfl_xor(p, off, 64);
            if (lane == 0) al_dst[r] = p + c;
        }
    } else {
        int idx0 = (blockIdx.x - 512) * 256 + threadIdx.x;
        for (int i = idx0; i < E; i += 1536 * 256) {
            int d = dstv[i];
            rank[i] = atomicAdd(&count8[(d << 3) | (i & (REP - 1))], 1);
        }
    }
}

// ---- group-base allocation over nt*REP bins: wave prefix-scan + one atomic per wave.
// Sub-bins 8n..8n+7 sit inside one wave -> contiguous ascending offsets per dst.
__global__ __launch_bounds__(256)
void alloc_kernel(const int* __restrict__ count8, int nbins, int* __restrict__ offs8,
                  int* __restrict__ total) {
    int gid = blockIdx.x * blockDim.x + threadIdx.x;
    int lane = threadIdx.x & 63;
    int v = (gid < nbins) ? count8[gid] : 0;
    int s = v;
    #pragma unroll
    for (int off = 1; off < 64; off <<= 1) {
        int t2 = __shfl_up(s, off, 64);
        if (lane >= off) s += t2;
    }
    int wavesum = __shfl(s, 63, 64);
    int base = 0;
    if (lane == 63) base = atomicAdd(total, wavesum);
    base = __shfl(base, 63, 64);
    if (gid < nbins) offs8[gid] = base + s - v;
}

// ---- scatter: ATOMIC-FREE. pos = offs8[sub-bin] + rank.
__global__ __launch_bounds__(256)
void scatter_kernel(const int* __restrict__ srcv, const int* __restrict__ dstv,
                    const int* __restrict__ rank, int E,
                    const int* __restrict__ offs8, uint* __restrict__ es) {
    int stride = gridDim.x * blockDim.x;
    for (int i = blockIdx.x * blockDim.x + threadIdx.x; i < E; i += stride) {
        int s = srcv[i], d = dstv[i], r = rank[i];
        es[offs8[(d << 3) | (i & (REP - 1))] + r] = (uint)s;
    }
}

// ---- per-dst: compute alpha in-register, softmax, gather-sum (bf16 h), relu+gelu
__global__ __launch_bounds__(256)
void agg_kernel(const ushort* __restrict__ h16, const int* __restrict__ offs8,
                const int* __restrict__ count8, const uint* __restrict__ es,
                const float* __restrict__ al_src, const float* __restrict__ al_dst,
                int nt, float* __restrict__ outp) {
    int lane = threadIdx.x & 63;
    int n = blockIdx.x * (blockDim.x >> 6) + (threadIdx.x >> 6);
    if (n >= nt) return;
    int beg = offs8[n << 3];
    int4 c0v = *(const int4*)&count8[n << 3];
    int4 c1v = *(const int4*)&count8[(n << 3) + 4];
    int cnt = c0v.x + c0v.y + c0v.z + c0v.w + c1v.x + c1v.y + c1v.z + c1v.w;
    float acc0 = 0.f, acc1 = 0.f;
    if (cnt > 0) {
        float ald = al_dst[n];
        uint s0 = 0, s1 = 0;
        float a0 = -1e30f, a1 = -1e30f;
        if (lane < cnt) {
            s0 = es[beg + lane];
            float t = al_src[s0] + ald; a0 = t > 0.f ? t : 0.2f * t;
        }
        if (64 + lane < cnt) {
            s1 = es[beg + 64 + lane];
            float t = al_src[s1] + ald; a1 = t > 0.f ? t : 0.2f * t;
        }
        float m = fmaxf(a0, a1);
        for (int i = 128 + lane; i < cnt; i += 64) {
            uint s = es[beg + i];
            float t = al_src[s] + ald; t = t > 0.f ? t : 0.2f * t;
            m = fmaxf(m, t);
        }
        #pragma unroll
        for (int off = 32; off; off >>= 1) m = fmaxf(m, __shfl_xor(m, off, 64));

        float w0 = (lane < cnt) ? __expf(a0 - m) : 0.f;
        float w1 = (64 + lane < cnt) ? __expf(a1 - m) : 0.f;
        float ssum = w0 + w1;
        for (int i = 128 + lane; i < cnt; i += 64) {
            uint s = es[beg + i];
            float t = al_src[s] + ald; t = t > 0.f ? t : 0.2f * t;
            ssum += __expf(t - m);
        }
        #pragma unroll
        for (int off = 32; off; off >>= 1) ssum += __shfl_xor(ssum, off, 64);
        float inv = 1.f / fmaxf(ssum, 1e-16f);

        for (int base = 0; base < cnt; base += 64) {
            uint pkl;
            if (base == 0)       pkl = (s0 << 16) | ((__float_as_uint(w0) + 0x8000u) >> 16);
            else if (base == 64) pkl = (s1 << 16) | ((__float_as_uint(w1) + 0x8000u) >> 16);
            else {
                pkl = 0;
                if (base + lane < cnt) {
                    uint s = es[beg + base + lane];
                    float t = al_src[s] + ald; t = t > 0.f ? t : 0.2f * t;
                    float wv = __expf(t - m);
                    pkl = (s << 16) | ((__float_as_uint(wv) + 0x8000u) >> 16);
                }
            }
            if (base + lane >= cnt) pkl = 0;
            int k = cnt - base; if (k > 64) k = 64;
            int kpad = (k + 7) & ~7;
            for (int i = 0; i < kpad; i += 8) {
                uint pk[8], hv[8];
                #pragma unroll
                for (int j = 0; j < 8; ++j) pk[j] = __shfl(pkl, i + j, 64);
                #pragma unroll
                for (int j = 0; j < 8; ++j) {
                    uint s2 = pk[j] >> 16;          // padded lanes -> row 0, w=0
                    hv[j] = ((const uint*)(h16 + (size_t)s2 * D))[lane];
                }
                #pragma unroll
                for (int j = 0; j < 8; ++j) {
                    float w  = __uint_as_float(pk[j] << 16);
                    float lo = __uint_as_float((hv[j] & 0xffffu) << 16);
                    float hi = __uint_as_float(hv[j] & 0xffff0000u);
                    acc0 = fmaf(w, lo, acc0);
                    acc1 = fmaf(w, hi, acc1);
                }
            }
        }
        acc0 *= inv; acc1 *= inv;
    }
    float o0 = acc0 > 0.f ? acc0 : 0.f;
    float o1 = acc1 > 0.f ? acc1 : 0.f;
    o0 = 0.5f * o0 * (1.f + erff(o0 * 0.70710678118654752f));
    o1 = 0.5f * o1 * (1.f + erff(o1 * 0.70710678118654752f));
    *(float2*)(outp + (size_t)n * D + 2 * lane) = make_float2(o0, o1);
}

extern "C" void kernel_launch(void* const* d_in, const int* in_sizes, int n_in,
                              void* d_out, int out_size, void* d_ws, size_t ws_size,
                              hipStream_t stream) {
    const float* x_ing   = (const float*)d_in[0];
    const float* x_taste = (const float*)d_in[1];
    const int*   edge    = (const int*)d_in[2];
    const float* W_ing   = (const float*)d_in[3];
    const float* b_ing   = (const float*)d_in[4];
    const float* W_taste = (const float*)d_in[5];
    const float* b_taste = (const float*)d_in[6];
    const float* a_src   = (const float*)d_in[7];
    const float* a_dst   = (const float*)d_in[8];
    // d_in[9..11] (Wk, bk, q) dead: softmax over single scalar -> beta == 1.
    float* outp = (float*)d_out;

    int Ni = in_sizes[0] / D;
    int Nt = in_sizes[1] / D;
    int E  = in_sizes[2] / 2;
    const int* srcv = edge;
    const int* dstv = edge + E;

    char* ws = (char*)d_ws;
    size_t off = 0;
    auto alloc = [&](size_t bytes) { void* p = ws + off; off += (bytes + 255) & ~(size_t)255; return p; };
    ushort* h16   = (ushort*)alloc((size_t)Ni * D * 2);
    ushort* Wt    = (ushort*)alloc((size_t)D * D * 2);
    float* v      = (float*)alloc(D * 4);
    float* consts = (float*)alloc(2 * 4);
    float* al_src = (float*)alloc((size_t)Ni * 4);
    float* al_dst = (float*)alloc((size_t)Nt * 4);
    int* count8   = (int*)alloc((size_t)Nt * REP * 4);
    int* offs8    = (int*)alloc((size_t)Nt * REP * 4);
    int* rank     = (int*)alloc((size_t)E * 4);
    int* total    = (int*)alloc(4);
    uint* es      = (uint*)alloc((size_t)E * 4);

    int nbins = Nt * REP;
    int zb = (nbins + 1 + 255) / 256;
    prep_kernel<<<3 + zb, 256, 0, stream>>>(W_ing, b_ing, W_taste, b_taste, a_src, a_dst,
                                            Wt, v, consts, count8, total, Nt);
    gemm_mfma<<<(Ni + 127) / 128, 256, 0, stream>>>(x_ing, Wt, b_ing, a_src, consts,
                                                    h16, al_src, Ni);
    mh_kernel<<<2048, 256, 0, stream>>>(x_taste, v, consts, Nt, al_dst, dstv, E, count8, rank);
    alloc_kernel<<<(nbins + 255) / 256, 256, 0, stream>>>(count8, nbins, offs8, total);
    scatter_kernel<<<1024, 256, 0, stream>>>(srcv, dstv, rank, E, offs8, es);
    agg_kernel<<<(Nt + 3) / 4, 256, 0, stream>>>(h16, offs8, count8, es, al_src, al_dst, Nt, outp);
}

// Round 9
// 87.643 us; speedup vs baseline: 1.3961x; 1.3961x over previous
//
#include <hip/hip_runtime.h>
#include <hip/hip_bf16.h>

#define D 128

using bf16x8 = __attribute__((ext_vector_type(8))) short;
using f32x4  = __attribute__((ext_vector_type(4))) float;

__device__ __forceinline__ ushort bf16bits(float f) {
    return __hip_bfloat16_raw(__float2bfloat16(f)).x;
}
__device__ __forceinline__ uint pack2(float lo, float hi) {
    return ((uint)bf16bits(hi) << 16) | (uint)bf16bits(lo);
}

// ---- prep: block0 = fold (v = W_taste@a_dst, consts); blocks1-2 = Wt = bf16(W_ing^T);
//      blocks3+ = zero count/total
__global__ __launch_bounds__(256)
void prep_kernel(const float* __restrict__ W_ing, const float* __restrict__ b_ing,
                 const float* __restrict__ W_taste, const float* __restrict__ b_taste,
                 const float* __restrict__ a_src, const float* __restrict__ a_dst,
                 ushort* __restrict__ Wt, float* __restrict__ v, float* __restrict__ consts,
                 int* __restrict__ count, int* __restrict__ total, int nt) {
    int t = threadIdx.x, b = blockIdx.x;
    if (b == 0) {
        __shared__ float red[D];
        int k = t;
        if (k < D) {
            float sv = 0.f;
            for (int d2 = 0; d2 < D; ++d2) sv += W_taste[k * D + d2] * a_dst[d2];
            v[k] = sv;
            red[k] = b_ing[k] * a_src[k];
        }
        __syncthreads();
        for (int s = 64; s > 0; s >>= 1) { if (k < s) red[k] += red[k + s]; __syncthreads(); }
        if (k == 0) consts[0] = red[0];
        __syncthreads();
        if (k < D) red[k] = b_taste[k] * a_dst[k];
        __syncthreads();
        for (int s = 64; s > 0; s >>= 1) { if (k < s) red[k] += red[k + s]; __syncthreads(); }
        if (k == 0) consts[1] = red[0];
    } else if (b <= 2) {
        int base = (b - 1) * 8192 + t * 32;
        #pragma unroll 8
        for (int i = 0; i < 32; ++i) {
            int idx = base + i;
            int n = idx >> 7, k = idx & 127;
            Wt[n * D + k] = bf16bits(W_ing[k * D + n]);
        }
    } else {
        int gid = (b - 3) * 256 + t;
        if (gid < nt) count[gid] = 0;
        if (gid == nt) *total = 0;
    }
}

// ---- fused front: [0,GB) MFMA gemm tiles | [GB,GB+512) al_dst matvec | [GB+512,GB+2048) hist
// gemm: h16 = bf16(x @ W_ing + b), fused al_src = h·a_src + consts[0]. BK=64 (32 KB LDS).
__global__ __launch_bounds__(256)
void front_kernel(const float* __restrict__ x, const ushort* __restrict__ Wt,
                  const float* __restrict__ b, const float* __restrict__ avec,
                  const float* __restrict__ consts,
                  ushort* __restrict__ h16, float* __restrict__ al, int nrows, int GB,
                  const float* __restrict__ x_taste, const float* __restrict__ v,
                  int nt, float* __restrict__ al_dst,
                  const int* __restrict__ dstv, int E, int* __restrict__ count,
                  int* __restrict__ rank) {
    __shared__ __align__(16) ushort Xs[128 * 64];   // 16 KB
    __shared__ __align__(16) ushort Ws[128 * 64];   // 16 KB
    int t = threadIdx.x;

    if (blockIdx.x >= GB) {
        int rb = blockIdx.x - GB;
        if (rb < 512) {
            // ---- al_dst matvec
            int lane = t & 63;
            int wave = rb * 4 + (t >> 6);
            float2 uv = ((const float2*)v)[lane];
            float c = consts[1];
            for (int r = wave; r < nt; r += 2048) {
                float2 xv = ((const float2*)(x_taste + (size_t)r * D))[lane];
                float p = xv.x * uv.x + xv.y * uv.y;
                #pragma unroll
                for (int off = 32; off; off >>= 1) p += __shfl_xor(p, off, 64);
                if (lane == 0) al_dst[r] = p + c;
            }
        } else {
            // ---- dst histogram; persist atomic return as rank
            int idx0 = (rb - 512) * 256 + t;
            for (int i = idx0; i < E; i += 1536 * 256)
                rank[i] = atomicAdd(&count[dstv[i]], 1);
        }
        return;
    }

    // ---- gemm tile: 128 rows x 128 cols, K staged in two 64-wide halves
    int row0 = blockIdx.x * 128;
    int l = t & 63, w = t >> 6;
    int lr = l & 15, lq = l >> 4;
    f32x4 acc[2][8];
    #pragma unroll
    for (int i = 0; i < 2; ++i)
        #pragma unroll
        for (int j = 0; j < 8; ++j) acc[i][j] = f32x4{0.f, 0.f, 0.f, 0.f};

    int rowA0 = w * 32 + lr;
    int rowA1 = rowA0 + 16;
    int sw = lr & 7;
    int r = t >> 1;
    int kh = (t & 1) * 32;                 // elem offset within 64-wide half-row
    bool valid = (row0 + r) < nrows;

    #pragma unroll
    for (int h = 0; h < 2; ++h) {
        int k0 = h * 64;
        {   // stage X (fp32->bf16) and Wt (bf16), 16B-chunk XOR-swizzled by (row&7)
            const float* xp = x + (size_t)(row0 + r) * D + k0 + kh;
            const ushort* wp = Wt + (size_t)r * D + k0 + kh;
            int base_us = r * 64;
            #pragma unroll
            for (int j = 0; j < 4; ++j) {
                int c16 = (kh >> 3) + j;   // 0..7
                int off = base_us + ((c16 ^ (r & 7)) << 3);
                float4 a = valid ? *(const float4*)(xp + j * 8)     : make_float4(0.f, 0.f, 0.f, 0.f);
                float4 c = valid ? *(const float4*)(xp + j * 8 + 4) : make_float4(0.f, 0.f, 0.f, 0.f);
                uint4 pk;
                pk.x = pack2(a.x, a.y); pk.y = pack2(a.z, a.w);
                pk.z = pack2(c.x, c.y); pk.w = pack2(c.z, c.w);
                *(uint4*)&Xs[off] = pk;
                *(uint4*)&Ws[off] = *(const uint4*)(wp + j * 8);
            }
        }
        __syncthreads();
        #pragma unroll
        for (int s = 0; s < 2; ++s) {
            int c16 = s * 4 + lq;          // 0..7
            bf16x8 A0 = *(const bf16x8*)&Xs[rowA0 * 64 + ((c16 ^ sw) << 3)];
            bf16x8 A1 = *(const bf16x8*)&Xs[rowA1 * 64 + ((c16 ^ sw) << 3)];
            #pragma unroll
            for (int ct = 0; ct < 8; ++ct) {
                int rn = ct * 16 + lr;
                bf16x8 B = *(const bf16x8*)&Ws[rn * 64 + ((c16 ^ sw) << 3)];
                acc[0][ct] = __builtin_amdgcn_mfma_f32_16x16x32_bf16(A0, B, acc[0][ct], 0, 0, 0);
                acc[1][ct] = __builtin_amdgcn_mfma_f32_16x16x32_bf16(A1, B, acc[1][ct], 0, 0, 0);
            }
        }
        __syncthreads();
    }

    float bv[8], av[8];
    #pragma unroll
    for (int ct = 0; ct < 8; ++ct) { bv[ct] = b[ct * 16 + lr]; av[ct] = avec[ct * 16 + lr]; }
    float c0 = consts[0];
    #pragma unroll
    for (int rt = 0; rt < 2; ++rt) {
        #pragma unroll
        for (int rr = 0; rr < 4; ++rr) {
            int gr = row0 + w * 32 + rt * 16 + lq * 4 + rr;
            float p = 0.f;
            ushort hrow[8];
            #pragma unroll
            for (int ct = 0; ct < 8; ++ct) {
                float hv = acc[rt][ct][rr] + bv[ct];
                p = fmaf(hv, av[ct], p);
                hrow[ct] = bf16bits(hv);
            }
            p += __shfl_xor(p, 1, 64); p += __shfl_xor(p, 2, 64);
            p += __shfl_xor(p, 4, 64); p += __shfl_xor(p, 8, 64);
            if (gr < nrows) {
                #pragma unroll
                for (int ct = 0; ct < 8; ++ct)
                    h16[(size_t)gr * D + ct * 16 + lr] = hrow[ct];
                if (lr == 0) al[gr] = p + c0;
            }
        }
    }
}

// ---- group-base allocation: wave prefix-scan + one atomic per wave
__global__ __launch_bounds__(256)
void alloc_kernel(const int* __restrict__ count, int n, int* __restrict__ offs,
                  int* __restrict__ total) {
    int gid = blockIdx.x * blockDim.x + threadIdx.x;
    int lane = threadIdx.x & 63;
    int v = (gid < n) ? count[gid] : 0;
    int s = v;
    #pragma unroll
    for (int off = 1; off < 64; off <<= 1) {
        int t2 = __shfl_up(s, off, 64);
        if (lane >= off) s += t2;
    }
    int wavesum = __shfl(s, 63, 64);
    int base = 0;
    if (lane == 63) base = atomicAdd(total, wavesum);
    base = __shfl(base, 63, 64);
    if (gid < n) offs[gid] = base + s - v;
}

// ---- scatter: ATOMIC-FREE. pos = offs[dst] + rank (precomputed by hist).
__global__ __launch_bounds__(256)
void scatter_kernel(const int* __restrict__ srcv, const int* __restrict__ dstv,
                    const int* __restrict__ rank, int E,
                    const int* __restrict__ offs, uint* __restrict__ es) {
    int stride = gridDim.x * blockDim.x;
    for (int i = blockIdx.x * blockDim.x + threadIdx.x; i < E; i += stride) {
        int s = srcv[i], d = dstv[i], r = rank[i];
        es[offs[d] + r] = (uint)s;
    }
}

// ---- per-dst: compute alpha in-register, softmax, gather-sum (bf16 h), relu+gelu
__global__ __launch_bounds__(256)
void agg_kernel(const ushort* __restrict__ h16, const int* __restrict__ offs,
                const int* __restrict__ count, const uint* __restrict__ es,
                const float* __restrict__ al_src, const float* __restrict__ al_dst,
                int nt, float* __restrict__ outp) {
    int lane = threadIdx.x & 63;
    int n = blockIdx.x * (blockDim.x >> 6) + (threadIdx.x >> 6);
    if (n >= nt) return;
    int beg = offs[n], cnt = count[n];
    float acc0 = 0.f, acc1 = 0.f;
    if (cnt > 0) {
        float ald = al_dst[n];
        uint s0 = 0, s1 = 0;
        float a0 = -1e30f, a1 = -1e30f;
        if (lane < cnt) {
            s0 = es[beg + lane];
            float t = al_src[s0] + ald; a0 = t > 0.f ? t : 0.2f * t;
        }
        if (64 + lane < cnt) {
            s1 = es[beg + 64 + lane];
            float t = al_src[s1] + ald; a1 = t > 0.f ? t : 0.2f * t;
        }
        float m = fmaxf(a0, a1);
        for (int i = 128 + lane; i < cnt; i += 64) {
            uint s = es[beg + i];
            float t = al_src[s] + ald; t = t > 0.f ? t : 0.2f * t;
            m = fmaxf(m, t);
        }
        #pragma unroll
        for (int off = 32; off; off >>= 1) m = fmaxf(m, __shfl_xor(m, off, 64));

        float w0 = (lane < cnt) ? __expf(a0 - m) : 0.f;
        float w1 = (64 + lane < cnt) ? __expf(a1 - m) : 0.f;
        float ssum = w0 + w1;
        for (int i = 128 + lane; i < cnt; i += 64) {
            uint s = es[beg + i];
            float t = al_src[s] + ald; t = t > 0.f ? t : 0.2f * t;
            ssum += __expf(t - m);
        }
        #pragma unroll
        for (int off = 32; off; off >>= 1) ssum += __shfl_xor(ssum, off, 64);
        float inv = 1.f / fmaxf(ssum, 1e-16f);

        for (int base = 0; base < cnt; base += 64) {
            uint pkl;
            if (base == 0)       pkl = (s0 << 16) | ((__float_as_uint(w0) + 0x8000u) >> 16);
            else if (base == 64) pkl = (s1 << 16) | ((__float_as_uint(w1) + 0x8000u) >> 16);
            else {
                pkl = 0;
                if (base + lane < cnt) {
                    uint s = es[beg + base + lane];
                    float t = al_src[s] + ald; t = t > 0.f ? t : 0.2f * t;
                    float wv = __expf(t - m);
                    pkl = (s << 16) | ((__float_as_uint(wv) + 0x8000u) >> 16);
                }
            }
            if (base + lane >= cnt) pkl = 0;
            int k = cnt - base; if (k > 64) k = 64;
            int kpad = (k + 7) & ~7;
            for (int i = 0; i < kpad; i += 8) {
                uint pk[8], hv[8];
                #pragma unroll
                for (int j = 0; j < 8; ++j) pk[j] = __shfl(pkl, i + j, 64);
                #pragma unroll
                for (int j = 0; j < 8; ++j) {
                    uint s2 = pk[j] >> 16;          // padded lanes -> row 0, w=0
                    hv[j] = ((const uint*)(h16 + (size_t)s2 * D))[lane];
                }
                #pragma unroll
                for (int j = 0; j < 8; ++j) {
                    float w  = __uint_as_float(pk[j] << 16);
                    float lo = __uint_as_float((hv[j] & 0xffffu) << 16);
                    float hi = __uint_as_float(hv[j] & 0xffff0000u);
                    acc0 = fmaf(w, lo, acc0);
                    acc1 = fmaf(w, hi, acc1);
                }
            }
        }
        acc0 *= inv; acc1 *= inv;
    }
    float o0 = acc0 > 0.f ? acc0 : 0.f;
    float o1 = acc1 > 0.f ? acc1 : 0.f;
    o0 = 0.5f * o0 * (1.f + erff(o0 * 0.70710678118654752f));
    o1 = 0.5f * o1 * (1.f + erff(o1 * 0.70710678118654752f));
    *(float2*)(outp + (size_t)n * D + 2 * lane) = make_float2(o0, o1);
}

extern "C" void kernel_launch(void* const* d_in, const int* in_sizes, int n_in,
                              void* d_out, int out_size, void* d_ws, size_t ws_size,
                              hipStream_t stream) {
    const float* x_ing   = (const float*)d_in[0];
    const float* x_taste = (const float*)d_in[1];
    const int*   edge    = (const int*)d_in[2];
    const float* W_ing   = (const float*)d_in[3];
    const float* b_ing   = (const float*)d_in[4];
    const float* W_taste = (const float*)d_in[5];
    const float* b_taste = (const float*)d_in[6];
    const float* a_src   = (const float*)d_in[7];
    const float* a_dst   = (const float*)d_in[8];
    // d_in[9..11] (Wk, bk, q) dead: softmax over single scalar -> beta == 1.
    float* outp = (float*)d_out;

    int Ni = in_sizes[0] / D;
    int Nt = in_sizes[1] / D;
    int E  = in_sizes[2] / 2;
    const int* srcv = edge;
    const int* dstv = edge + E;

    char* ws = (char*)d_ws;
    size_t off = 0;
    auto alloc = [&](size_t bytes) { void* p = ws + off; off += (bytes + 255) & ~(size_t)255; return p; };
    ushort* h16   = (ushort*)alloc((size_t)Ni * D * 2);
    ushort* Wt    = (ushort*)alloc((size_t)D * D * 2);
    float* v      = (float*)alloc(D * 4);
    float* consts = (float*)alloc(2 * 4);
    float* al_src = (float*)alloc((size_t)Ni * 4);
    float* al_dst = (float*)alloc((size_t)Nt * 4);
    int* count    = (int*)alloc((size_t)Nt * 4);
    int* offs     = (int*)alloc((size_t)Nt * 4);
    int* rank     = (int*)alloc((size_t)E * 4);
    int* total    = (int*)alloc(4);
    uint* es      = (uint*)alloc((size_t)E * 4);

    int GB = (Ni + 127) / 128;
    int zb = (Nt + 1 + 255) / 256;
    prep_kernel<<<3 + zb, 256, 0, stream>>>(W_ing, b_ing, W_taste, b_taste, a_src, a_dst,
                                            Wt, v, consts, count, total, Nt);
    front_kernel<<<GB + 2048, 256, 0, stream>>>(x_ing, Wt, b_ing, a_src, consts,
                                                h16, al_src, Ni, GB,
                                                x_taste, v, Nt, al_dst,
                                                dstv, E, count, rank);
    alloc_kernel<<<(Nt + 255) / 256, 256, 0, stream>>>(count, Nt, offs, total);
    scatter_kernel<<<1024, 256, 0, stream>>>(srcv, dstv, rank, E, offs, es);
    agg_kernel<<<(Nt + 3) / 4, 256, 0, stream>>>(h16, offs, count, es, al_src, al_dst, Nt, outp);
}